// Round 8
// baseline (223.410 us; speedup 1.0000x reference)
//
#include <hip/hip_runtime.h>
#include <hip/hip_cooperative_groups.h>
#include <math.h>

namespace cg = cooperative_groups;

#define NN 384
#define IN_F 64
#define HID 32
#define RR 16
#define HP_W 1024   // 2*R*HID
#define EPSF 1e-5f
#define CHUNK 48
#define NCHUNK 8    // NN / CHUNK
#define MT 2        // m values per mid-phase block
#define VB_TOTAL 1536

typedef float f4 __attribute__((ext_vector_type(4)));

// ==================== fused cooperative kernel (grid-stride phases) ====================
__global__ __launch_bounds__(256) void k_fused(const float* __restrict__ x,
                                               const float* __restrict__ h,
                                               const float* __restrict__ Wfc,
                                               const float* __restrict__ Wsum,
                                               const float* __restrict__ bsum,
                                               float* __restrict__ hpT,
                                               float* __restrict__ pbk,
                                               float* __restrict__ pS,
                                               float* __restrict__ outv,
                                               float* __restrict__ out,
                                               float beta, float start) {
    cg::grid_group grid = cg::this_grid();
    const int tid = threadIdx.x;

    __shared__ float smear_s[MT][CHUNK][16];   // 6 KB
    __shared__ float dxn_s[MT][CHUNK][3];
    __shared__ float red_s[4][MT][64][3];      // 6 KB
    __shared__ float S_s[16][3];
    __shared__ float bkq_s[2][HID][3];
    __shared__ float silu_s[HID];
    __shared__ float4 om[32];

    // ---------------- phase 1: hp^T (vb -> m = vb>>2, quarter q = vb&3); no LDS ----------------
    for (int vb = blockIdx.x; vb < NN * 4; vb += gridDim.x) {
        const int m = vb >> 2, q = vb & 3;
        const int j = q * 256 + tid;            // j = kq*512 + r*32 + c
        const float4* hrow = (const float4*)(h + m * IN_F);   // wave-uniform (L1 broadcast)
        const float4* row = (const float4*)Wfc + (size_t)j * (IN_F / 4);
        float acc = 0.f;
#pragma unroll
        for (int k = 0; k < IN_F / 4; ++k) {
            float4 w = row[k];
            float4 hv = hrow[k];
            acc += w.x * hv.x + w.y * hv.y + w.z * hv.z + w.w * hv.w;
        }
        const int kq = j >> 9, rc = j & 511, r = rc >> 5, c = rc & 31;
        hpT[(size_t)m * HP_W + kq * 512 + c * 16 + r] = acc;   // [kq][c][r]
    }
    grid.sync();

    // ---------------- phase 2: mid (vb -> ch = vb&7, m-group = vb>>3) ----------------
    for (int vb = blockIdx.x; vb < VB_TOTAL; vb += gridDim.x) {
        const int ch = vb & 7;
        const int m0 = (vb >> 3) * MT;
        const int n0 = ch * CHUNK;

        for (int it = tid; it < MT * CHUNK * 16; it += 256) {
            int mi = it / (CHUNK * 16);
            int rest = it % (CHUNK * 16);
            int np = rest >> 4, r = rest & 15;
            int m = m0 + mi, n = n0 + np;
            float d0 = x[m * 3 + 0] - x[n * 3 + 0];
            float d1 = x[m * 3 + 1] - x[n * 3 + 1];
            float d2 = x[m * 3 + 2] - x[n * 3 + 2];
            float nsq = d0 * d0 + d1 * d1 + d2 * d2 + EPSF;
            float dist = sqrtf(nsq);
            float cut = (dist < 5.0f) ? 0.5f * (__cosf(dist * 0.62831853071795864769f) + 1.0f) : 0.0f;
            float en = __expf(-dist);
            float mean_r = start + (1.0f - start) * ((float)r * (1.0f / 15.0f));
            float dmr = en - mean_r;
            smear_s[mi][np][r] = cut * __expf(-beta * dmr * dmr);
            if (r < 3) dxn_s[mi][np][r] = ((r == 0) ? d0 : ((r == 1) ? d1 : d2)) / nsq;
        }
        __syncthreads();

        const int g = tid >> 6, kq = (tid >> 5) & 1, c = tid & 31;
        float a00 = 0.f, a01 = 0.f, a02 = 0.f, a10 = 0.f, a11 = 0.f, a12 = 0.f;
        const float* hpbase = hpT + (size_t)(n0 + g * 12) * HP_W + kq * 512 + c * 16;
        for (int ni = 0; ni < 12; ++ni) {
            const int np = g * 12 + ni;
            const float4* hp4 = (const float4*)(hpbase + (size_t)ni * HP_W);
            float4 h0 = hp4[0], h1 = hp4[1], h2 = hp4[2], h3 = hp4[3];
            {
                const float4* sm4 = (const float4*)smear_s[0][np];
                float4 s0 = sm4[0], s1 = sm4[1], s2 = sm4[2], s3 = sm4[3];
                float P = h0.x * s0.x + h0.y * s0.y + h0.z * s0.z + h0.w * s0.w
                        + h1.x * s1.x + h1.y * s1.y + h1.z * s1.z + h1.w * s1.w
                        + h2.x * s2.x + h2.y * s2.y + h2.z * s2.z + h2.w * s2.w
                        + h3.x * s3.x + h3.y * s3.y + h3.z * s3.z + h3.w * s3.w;
                a00 += P * dxn_s[0][np][0];
                a01 += P * dxn_s[0][np][1];
                a02 += P * dxn_s[0][np][2];
            }
            {
                const float4* sm4 = (const float4*)smear_s[1][np];
                float4 s0 = sm4[0], s1 = sm4[1], s2 = sm4[2], s3 = sm4[3];
                float P = h0.x * s0.x + h0.y * s0.y + h0.z * s0.z + h0.w * s0.w
                        + h1.x * s1.x + h1.y * s1.y + h1.z * s1.z + h1.w * s1.w
                        + h2.x * s2.x + h2.y * s2.y + h2.z * s2.z + h2.w * s2.w
                        + h3.x * s3.x + h3.y * s3.y + h3.z * s3.z + h3.w * s3.w;
                a10 += P * dxn_s[1][np][0];
                a11 += P * dxn_s[1][np][1];
                a12 += P * dxn_s[1][np][2];
            }
        }
        red_s[g][0][kq * 32 + c][0] = a00;
        red_s[g][0][kq * 32 + c][1] = a01;
        red_s[g][0][kq * 32 + c][2] = a02;
        red_s[g][1][kq * 32 + c][0] = a10;
        red_s[g][1][kq * 32 + c][1] = a11;
        red_s[g][1][kq * 32 + c][2] = a12;

        float accS = 0.f;
        int smi = 0, ss = 0;
        if (tid < MT * 48) {
            smi = tid / 48; ss = tid % 48;
            const int r = ss / 3, bb = ss % 3;
            for (int np = 0; np < CHUNK; ++np)
                accS += smear_s[smi][np][r] * dxn_s[smi][np][bb];
        }
        __syncthreads();

        for (int it = tid; it < MT * 192; it += 256) {
            int mi = it / 192, j = it % 192;
            int kq2 = j / 96, b2 = (j % 96) / 32, c2 = j % 32;
            float v = red_s[0][mi][kq2 * 32 + c2][b2] + red_s[1][mi][kq2 * 32 + c2][b2]
                    + red_s[2][mi][kq2 * 32 + c2][b2] + red_s[3][mi][kq2 * 32 + c2][b2];
            pbk[((size_t)(m0 + mi) * NCHUNK + ch) * 192 + j] = v;
        }
        if (tid < MT * 48)
            pS[((size_t)(m0 + smi) * NCHUNK + ch) * 48 + ss] = accS;
    }
    grid.sync();

    // ---------------- phase 3: combine (vb = m over 0..383) ----------------
    for (int vb = blockIdx.x; vb < NN; vb += gridDim.x) {
        const int m = vb;
        float v = 0.f;
        if (tid < 192) {
            for (int chn = 0; chn < NCHUNK; ++chn)
                v += pbk[((size_t)m * NCHUNK + chn) * 192 + tid];
        } else if (tid < 240) {
            int s = tid - 192;
            float a = 0.f;
            for (int chn = 0; chn < NCHUNK; ++chn)
                a += pS[((size_t)m * NCHUNK + chn) * 48 + s];
            S_s[s / 3][s % 3] = a;
        }
        __syncthreads();
        if (tid < 192) {
            const int kq = tid / 96, bb = (tid % 96) / 32, cc = tid % 32;
            const float4* hb = (const float4*)(hpT + (size_t)m * HP_W + kq * 512 + cc * 16);
            float4 h0 = hb[0], h1 = hb[1], h2 = hb[2], h3 = hb[3];
            v += h0.x * S_s[0][bb] + h0.y * S_s[1][bb] + h0.z * S_s[2][bb] + h0.w * S_s[3][bb]
               + h1.x * S_s[4][bb] + h1.y * S_s[5][bb] + h1.z * S_s[6][bb] + h1.w * S_s[7][bb]
               + h2.x * S_s[8][bb] + h2.y * S_s[9][bb] + h2.z * S_s[10][bb] + h2.w * S_s[11][bb]
               + h3.x * S_s[12][bb] + h3.y * S_s[13][bb] + h3.z * S_s[14][bb] + h3.w * S_s[15][bb];
            bkq_s[kq][cc][bb] = v;
        }
        __syncthreads();
        if (tid < HID) {
            float a = bkq_s[0][tid][0] * bkq_s[1][tid][0]
                    + bkq_s[0][tid][1] * bkq_s[1][tid][1]
                    + bkq_s[0][tid][2] * bkq_s[1][tid][2];
            silu_s[tid] = a / (1.0f + __expf(-a));
        }
        __syncthreads();
        if (tid < 128) {
            float acc = bsum[tid];
            const float* wr = Wsum + tid * HID;
#pragma unroll
            for (int c2 = 0; c2 < HID; ++c2) acc += wr[c2] * silu_s[c2];
            outv[(size_t)m * 128 + tid] = acc;
        }
        __syncthreads();   // protect S_s/bkq_s/silu_s reuse across loop iterations
    }
    grid.sync();

    // ---------------- phase 4: expand (vb -> m = vb>>2, 6 strips of 16 n) ----------------
    for (int vb = blockIdx.x; vb < NN * 4; vb += gridDim.x) {
        const int m = vb >> 2;
        if (tid < 32) om[tid] = ((const float4*)(outv + (size_t)m * 128))[tid];
        __syncthreads();
        const int ni = tid >> 4, r = tid & 15;
        const float4 a0 = om[2 * r], a1 = om[2 * r + 1];
        f4* o4 = (f4*)out;
#pragma unroll
        for (int i = 0; i < 6; ++i) {
            const int n = ((vb & 3) * 6 + i) * 16 + ni;
            const float4* on = (const float4*)(outv + (size_t)n * 128);
            float4 b0 = on[2 * r], b1 = on[2 * r + 1];
            f4 k2 = {a0.x + b0.x, a0.y + b0.y, a0.z + b0.z, a0.w + b0.w};
            f4 q2 = {a1.x + b1.x, a1.y + b1.y, a1.z + b1.z, a1.w + b1.w};
            const size_t idx = ((size_t)(m * NN + n) * RR + r);
            __builtin_nontemporal_store(k2, o4 + idx);
            __builtin_nontemporal_store(q2, o4 + (size_t)NN * NN * RR + idx);
        }
        __syncthreads();   // protect om reuse across loop iterations
    }
}

// ==================== fallback chain (round-6 proven, 68.7 us) ====================
__global__ __launch_bounds__(256) void k_hp(const float* __restrict__ h,
                                            const float* __restrict__ Wfc,
                                            float* __restrict__ hpT) {
    int m = blockIdx.x;
    int tid = threadIdx.x;
    __shared__ float4 hs4[IN_F / 4];
    if (tid < IN_F / 4) hs4[tid] = ((const float4*)(h + m * IN_F))[tid];
    __syncthreads();
    const float4* W4 = (const float4*)Wfc;
    for (int jj = 0; jj < 4; ++jj) {
        int j = tid + 256 * jj;
        const float4* row = W4 + (size_t)j * (IN_F / 4);
        float acc = 0.f;
#pragma unroll
        for (int k = 0; k < IN_F / 4; ++k) {
            float4 w = row[k];
            float4 hv = hs4[k];
            acc += w.x * hv.x + w.y * hv.y + w.z * hv.z + w.w * hv.w;
        }
        int kq = j >> 9, rc = j & 511, r = rc >> 5, c = rc & 31;
        hpT[(size_t)m * HP_W + kq * 512 + c * 16 + r] = acc;
    }
}

__global__ __launch_bounds__(256) void k_mid(const float* __restrict__ x,
                                             const float* __restrict__ hpT,
                                             float* __restrict__ pbk,
                                             float* __restrict__ pS,
                                             float beta, float start) {
    const int ch = blockIdx.x;
    const int m0 = blockIdx.y * MT;
    const int n0 = ch * CHUNK;
    const int tid = threadIdx.x;

    __shared__ float smear_s[MT][CHUNK][16];
    __shared__ float dxn_s[MT][CHUNK][3];
    __shared__ float red_s[4][MT][64][3];

    for (int it = tid; it < MT * CHUNK * 16; it += 256) {
        int mi = it / (CHUNK * 16);
        int rest = it % (CHUNK * 16);
        int np = rest >> 4, r = rest & 15;
        int m = m0 + mi, n = n0 + np;
        float d0 = x[m * 3 + 0] - x[n * 3 + 0];
        float d1 = x[m * 3 + 1] - x[n * 3 + 1];
        float d2 = x[m * 3 + 2] - x[n * 3 + 2];
        float nsq = d0 * d0 + d1 * d1 + d2 * d2 + EPSF;
        float dist = sqrtf(nsq);
        float cut = (dist < 5.0f) ? 0.5f * (__cosf(dist * 0.62831853071795864769f) + 1.0f) : 0.0f;
        float en = __expf(-dist);
        float mean_r = start + (1.0f - start) * ((float)r * (1.0f / 15.0f));
        float dmr = en - mean_r;
        smear_s[mi][np][r] = cut * __expf(-beta * dmr * dmr);
        if (r < 3) dxn_s[mi][np][r] = ((r == 0) ? d0 : ((r == 1) ? d1 : d2)) / nsq;
    }
    __syncthreads();

    const int g = tid >> 6, kq = (tid >> 5) & 1, c = tid & 31;
    float a00 = 0.f, a01 = 0.f, a02 = 0.f, a10 = 0.f, a11 = 0.f, a12 = 0.f;
    const float* hpbase = hpT + (size_t)(n0 + g * 12) * HP_W + kq * 512 + c * 16;
    for (int ni = 0; ni < 12; ++ni) {
        const int np = g * 12 + ni;
        const float4* hp4 = (const float4*)(hpbase + (size_t)ni * HP_W);
        float4 h0 = hp4[0], h1 = hp4[1], h2 = hp4[2], h3 = hp4[3];
        {
            const float4* sm4 = (const float4*)smear_s[0][np];
            float4 s0 = sm4[0], s1 = sm4[1], s2 = sm4[2], s3 = sm4[3];
            float P = h0.x * s0.x + h0.y * s0.y + h0.z * s0.z + h0.w * s0.w
                    + h1.x * s1.x + h1.y * s1.y + h1.z * s1.z + h1.w * s1.w
                    + h2.x * s2.x + h2.y * s2.y + h2.z * s2.z + h2.w * s2.w
                    + h3.x * s3.x + h3.y * s3.y + h3.z * s3.z + h3.w * s3.w;
            a00 += P * dxn_s[0][np][0];
            a01 += P * dxn_s[0][np][1];
            a02 += P * dxn_s[0][np][2];
        }
        {
            const float4* sm4 = (const float4*)smear_s[1][np];
            float4 s0 = sm4[0], s1 = sm4[1], s2 = sm4[2], s3 = sm4[3];
            float P = h0.x * s0.x + h0.y * s0.y + h0.z * s0.z + h0.w * s0.w
                    + h1.x * s1.x + h1.y * s1.y + h1.z * s1.z + h1.w * s1.w
                    + h2.x * s2.x + h2.y * s2.y + h2.z * s2.z + h2.w * s2.w
                    + h3.x * s3.x + h3.y * s3.y + h3.z * s3.z + h3.w * s3.w;
            a10 += P * dxn_s[1][np][0];
            a11 += P * dxn_s[1][np][1];
            a12 += P * dxn_s[1][np][2];
        }
    }
    red_s[g][0][kq * 32 + c][0] = a00;
    red_s[g][0][kq * 32 + c][1] = a01;
    red_s[g][0][kq * 32 + c][2] = a02;
    red_s[g][1][kq * 32 + c][0] = a10;
    red_s[g][1][kq * 32 + c][1] = a11;
    red_s[g][1][kq * 32 + c][2] = a12;

    float accS = 0.f;
    int smi = 0, ss = 0;
    if (tid < MT * 48) {
        smi = tid / 48; ss = tid % 48;
        const int r = ss / 3, b = ss % 3;
        for (int np = 0; np < CHUNK; ++np)
            accS += smear_s[smi][np][r] * dxn_s[smi][np][b];
    }
    __syncthreads();

    for (int it = tid; it < MT * 192; it += 256) {
        int mi = it / 192, j = it % 192;
        int kq2 = j / 96, b2 = (j % 96) / 32, c2 = j % 32;
        float v = red_s[0][mi][kq2 * 32 + c2][b2] + red_s[1][mi][kq2 * 32 + c2][b2]
                + red_s[2][mi][kq2 * 32 + c2][b2] + red_s[3][mi][kq2 * 32 + c2][b2];
        pbk[((size_t)(m0 + mi) * NCHUNK + ch) * 192 + j] = v;
    }
    if (tid < MT * 48)
        pS[((size_t)(m0 + smi) * NCHUNK + ch) * 48 + ss] = accS;
}

__global__ __launch_bounds__(256) void k_combine(const float* __restrict__ hpT,
                                                 const float* __restrict__ Wsum,
                                                 const float* __restrict__ bsum,
                                                 const float* __restrict__ pbk,
                                                 const float* __restrict__ pS,
                                                 float* __restrict__ outv) {
    const int m = blockIdx.x;
    const int tid = threadIdx.x;
    __shared__ float S_s[16][3];
    __shared__ float bkq_s[2][HID][3];
    __shared__ float silu_s[HID];

    float v = 0.f;
    if (tid < 192) {
        for (int chn = 0; chn < NCHUNK; ++chn)
            v += pbk[((size_t)m * NCHUNK + chn) * 192 + tid];
    } else if (tid < 240) {
        int s = tid - 192;
        float a = 0.f;
        for (int chn = 0; chn < NCHUNK; ++chn)
            a += pS[((size_t)m * NCHUNK + chn) * 48 + s];
        S_s[s / 3][s % 3] = a;
    }
    __syncthreads();
    if (tid < 192) {
        const int kq = tid / 96, b = (tid % 96) / 32, cc = tid % 32;
        const float4* hb = (const float4*)(hpT + (size_t)m * HP_W + kq * 512 + cc * 16);
        float4 h0 = hb[0], h1 = hb[1], h2 = hb[2], h3 = hb[3];
        v += h0.x * S_s[0][b] + h0.y * S_s[1][b] + h0.z * S_s[2][b] + h0.w * S_s[3][b]
           + h1.x * S_s[4][b] + h1.y * S_s[5][b] + h1.z * S_s[6][b] + h1.w * S_s[7][b]
           + h2.x * S_s[8][b] + h2.y * S_s[9][b] + h2.z * S_s[10][b] + h2.w * S_s[11][b]
           + h3.x * S_s[12][b] + h3.y * S_s[13][b] + h3.z * S_s[14][b] + h3.w * S_s[15][b];
        bkq_s[kq][cc][b] = v;
    }
    __syncthreads();
    if (tid < HID) {
        float a = bkq_s[0][tid][0] * bkq_s[1][tid][0]
                + bkq_s[0][tid][1] * bkq_s[1][tid][1]
                + bkq_s[0][tid][2] * bkq_s[1][tid][2];
        silu_s[tid] = a / (1.0f + __expf(-a));
    }
    __syncthreads();
    if (tid < 128) {
        float acc = bsum[tid];
        const float* wr = Wsum + tid * HID;
#pragma unroll
        for (int c2 = 0; c2 < HID; ++c2) acc += wr[c2] * silu_s[c2];
        outv[(size_t)m * 128 + tid] = acc;
    }
}

__global__ __launch_bounds__(256) void k_expand(const float* __restrict__ outv,
                                                float* __restrict__ out) {
    const int bid = blockIdx.x;
    const int m = bid / 24;
    const int n0 = (bid % 24) * 16;
    const int tid = threadIdx.x;
    __shared__ float4 om[32];
    if (tid < 32) om[tid] = ((const float4*)(outv + (size_t)m * 128))[tid];
    __syncthreads();
    const int ni = tid >> 4;
    const int r = tid & 15;
    const int n = n0 + ni;
    const float4* on = (const float4*)(outv + (size_t)n * 128);
    float4 a0 = om[2 * r], a1 = om[2 * r + 1];
    float4 b0 = on[2 * r], b1 = on[2 * r + 1];
    f4 k2 = {a0.x + b0.x, a0.y + b0.y, a0.z + b0.z, a0.w + b0.w};
    f4 q2 = {a1.x + b1.x, a1.y + b1.y, a1.z + b1.z, a1.w + b1.w};
    f4* o4 = (f4*)out;
    const size_t idx = ((size_t)(m * NN + n) * RR + r);
    __builtin_nontemporal_store(k2, o4 + idx);
    __builtin_nontemporal_store(q2, o4 + (size_t)NN * NN * RR + idx);
}

extern "C" void kernel_launch(void* const* d_in, const int* in_sizes, int n_in,
                              void* d_out, int out_size, void* d_ws, size_t ws_size,
                              hipStream_t stream) {
    const float* x    = (const float*)d_in[0];
    const float* h    = (const float*)d_in[1];
    const float* Wfc  = (const float*)d_in[2];
    const float* Wsum = (const float*)d_in[3];
    const float* bsum = (const float*)d_in[4];
    float* out = (float*)d_out;

    float* hpT  = (float*)d_ws;                         // 384*1024
    float* pbk  = hpT + (size_t)NN * HP_W;              // 384*8*192
    float* pS   = pbk + (size_t)NN * NCHUNK * 192;      // 384*8*48
    float* outv = pS + (size_t)NN * NCHUNK * 48;        // 384*128

    double startd = exp(-5.0);
    double rd = (2.0 / 16.0) * (1.0 - startd);
    float beta = (float)(1.0 / (rd * rd));
    float start = (float)startd;

    // attempt cooperative single-kernel launch, clamped to guaranteed co-residency
    bool coop_ok = false;
    int occ = 0;
    hipError_t oerr = hipOccupancyMaxActiveBlocksPerMultiprocessor(&occ, k_fused, 256, 0);
    if (oerr == hipSuccess && occ > 0) {
        int gridN = occ * 256;                  // 256 CUs on MI355X
        if (gridN > VB_TOTAL) gridN = VB_TOTAL;
        void* args[] = {(void*)&x, (void*)&h, (void*)&Wfc, (void*)&Wsum, (void*)&bsum,
                        (void*)&hpT, (void*)&pbk, (void*)&pS, (void*)&outv, (void*)&out,
                        (void*)&beta, (void*)&start};
        hipError_t lerr = hipLaunchCooperativeKernel((const void*)k_fused, dim3(gridN),
                                                     dim3(256), args, 0, stream);
        coop_ok = (lerr == hipSuccess);
    }

    if (!coop_ok) {
        // proven 4-kernel fallback (round 6, 68.7 us)
        k_hp<<<NN, 256, 0, stream>>>(h, Wfc, hpT);
        k_mid<<<dim3(NCHUNK, NN / MT), 256, 0, stream>>>(x, hpT, pbk, pS, beta, start);
        k_combine<<<NN, 256, 0, stream>>>(hpT, Wsum, bsum, pbk, pS, outv);
        k_expand<<<NN * 24, 256, 0, stream>>>(outv, out);
    }
}

// Round 9
// 65.276 us; speedup vs baseline: 3.4225x; 3.4225x over previous
//
#include <hip/hip_runtime.h>
#include <math.h>

#define NN 384
#define IN_F 64
#define HID 32
#define RR 16
#define HP_W 1024   // 2*R*HID
#define EPSF 1e-5f
#define CHUNK 48
#define NCHUNK 8    // NN / CHUNK
#define MT 4        // m values per k_mid block (round 9: 2 -> 4, halves hpT L2 traffic)

typedef float f4 __attribute__((ext_vector_type(4)));

// ---------------- kernel 1: hp^T[m][kq][c][r] = h @ W_fc^T (transposed store) ----------------
__global__ __launch_bounds__(256) void k_hp(const float* __restrict__ h,
                                            const float* __restrict__ Wfc,
                                            float* __restrict__ hpT) {
    int m = blockIdx.x;
    int tid = threadIdx.x;
    __shared__ float4 hs4[IN_F / 4];
    if (tid < IN_F / 4) hs4[tid] = ((const float4*)(h + m * IN_F))[tid];
    __syncthreads();
    const float4* W4 = (const float4*)Wfc;
    for (int jj = 0; jj < 4; ++jj) {
        int j = tid + 256 * jj;                 // j = kq*512 + r*32 + c
        const float4* row = W4 + (size_t)j * (IN_F / 4);
        float acc = 0.f;
#pragma unroll
        for (int k = 0; k < IN_F / 4; ++k) {
            float4 w = row[k];
            float4 hv = hs4[k];
            acc += w.x * hv.x + w.y * hv.y + w.z * hv.z + w.w * hv.w;
        }
        int kq = j >> 9, rc = j & 511, r = rc >> 5, c = rc & 31;
        hpT[(size_t)m * HP_W + kq * 512 + c * 16 + r] = acc;   // [kq][c][r]
    }
}

// ---------------- kernel 2: partial reduction over an n-chunk for MT=4 m's ----------------
// pbk[m][ch][kq*96+b*32+c] = sum_{n in chunk} dxn[m,n,b] * (sum_r smear[m,n,r]*hpT[n,kq,c,r])
// pS [m][ch][r*3+b]        = sum_{n in chunk} smear[m,n,r]*dxn[m,n,b]
__global__ __launch_bounds__(256) void k_mid(const float* __restrict__ x,
                                             const float* __restrict__ hpT,
                                             float* __restrict__ pbk,
                                             float* __restrict__ pS,
                                             float beta, float start) {
    const int ch = blockIdx.x;
    const int m0 = blockIdx.y * MT;
    const int n0 = ch * CHUNK;
    const int tid = threadIdx.x;

    __shared__ float smear_s[MT][CHUNK][16];   // 12 KB
    __shared__ float dxn_s[MT][CHUNK][3];      // 2.3 KB
    __shared__ float red_s[4][MT][64][3];      // 12 KB

    // phase 1: geometry (MT*CHUNK*16 = 3072 items)
    for (int it = tid; it < MT * CHUNK * 16; it += 256) {
        int mi = it / (CHUNK * 16);
        int rest = it % (CHUNK * 16);
        int np = rest >> 4, r = rest & 15;
        int m = m0 + mi, n = n0 + np;
        float d0 = x[m * 3 + 0] - x[n * 3 + 0];
        float d1 = x[m * 3 + 1] - x[n * 3 + 1];
        float d2 = x[m * 3 + 2] - x[n * 3 + 2];
        float nsq = d0 * d0 + d1 * d1 + d2 * d2 + EPSF;
        float dist = sqrtf(nsq);
        float cut = (dist < 5.0f) ? 0.5f * (__cosf(dist * 0.62831853071795864769f) + 1.0f) : 0.0f;
        float en = __expf(-dist);
        float mean_r = start + (1.0f - start) * ((float)r * (1.0f / 15.0f));
        float dmr = en - mean_r;
        smear_s[mi][np][r] = cut * __expf(-beta * dmr * dmr);
        if (r < 3) dxn_s[mi][np][r] = ((r == 0) ? d0 : ((r == 1) ? d1 : d2)) / nsq;
    }
    __syncthreads();

    // phase 2: thread (g, kq, c); g covers 12 n; each hp row feeds all 4 m
    const int g = tid >> 6, kq = (tid >> 5) & 1, c = tid & 31;
    float acc[MT][3];
#pragma unroll
    for (int mi = 0; mi < MT; ++mi) { acc[mi][0] = 0.f; acc[mi][1] = 0.f; acc[mi][2] = 0.f; }
    const float* hpbase = hpT + (size_t)(n0 + g * 12) * HP_W + kq * 512 + c * 16;
    for (int ni = 0; ni < 12; ++ni) {
        const int np = g * 12 + ni;
        const float4* hp4 = (const float4*)(hpbase + (size_t)ni * HP_W);
        float4 h0 = hp4[0], h1 = hp4[1], h2 = hp4[2], h3 = hp4[3];
#pragma unroll
        for (int mi = 0; mi < MT; ++mi) {
            const float4* sm4 = (const float4*)smear_s[mi][np];
            float4 s0 = sm4[0], s1 = sm4[1], s2 = sm4[2], s3 = sm4[3];
            float P = h0.x * s0.x + h0.y * s0.y + h0.z * s0.z + h0.w * s0.w
                    + h1.x * s1.x + h1.y * s1.y + h1.z * s1.z + h1.w * s1.w
                    + h2.x * s2.x + h2.y * s2.y + h2.z * s2.z + h2.w * s2.w
                    + h3.x * s3.x + h3.y * s3.y + h3.z * s3.z + h3.w * s3.w;
            acc[mi][0] += P * dxn_s[mi][np][0];
            acc[mi][1] += P * dxn_s[mi][np][1];
            acc[mi][2] += P * dxn_s[mi][np][2];
        }
    }
#pragma unroll
    for (int mi = 0; mi < MT; ++mi) {
        red_s[g][mi][kq * 32 + c][0] = acc[mi][0];
        red_s[g][mi][kq * 32 + c][1] = acc[mi][1];
        red_s[g][mi][kq * 32 + c][2] = acc[mi][2];
    }

    // S phase (reads only phase-1 LDS; no barrier needed before it)
    float accS = 0.f;
    int smi = 0, ss = 0;
    if (tid < MT * 48) {
        smi = tid / 48; ss = tid % 48;
        const int r = ss / 3, b = ss % 3;
        for (int np = 0; np < CHUNK; ++np)
            accS += smear_s[smi][np][r] * dxn_s[smi][np][b];
    }
    __syncthreads();

    // write partials (MT*192 = 768 items)
    for (int it = tid; it < MT * 192; it += 256) {
        int mi = it / 192, j = it % 192;
        int kq2 = j / 96, b2 = (j % 96) / 32, c2 = j % 32;
        float v = red_s[0][mi][kq2 * 32 + c2][b2] + red_s[1][mi][kq2 * 32 + c2][b2]
                + red_s[2][mi][kq2 * 32 + c2][b2] + red_s[3][mi][kq2 * 32 + c2][b2];
        pbk[((size_t)(m0 + mi) * NCHUNK + ch) * 192 + j] = v;
    }
    if (tid < MT * 48)
        pS[((size_t)(m0 + smi) * NCHUNK + ch) * 48 + ss] = accS;
}

// ---------------- kernel 3: combine partials + epilogue -> outv[m][128] ----------------
__global__ __launch_bounds__(256) void k_combine(const float* __restrict__ hpT,
                                                 const float* __restrict__ Wsum,
                                                 const float* __restrict__ bsum,
                                                 const float* __restrict__ pbk,
                                                 const float* __restrict__ pS,
                                                 float* __restrict__ outv) {
    const int m = blockIdx.x;
    const int tid = threadIdx.x;
    __shared__ float S_s[16][3];
    __shared__ float bkq_s[2][HID][3];
    __shared__ float silu_s[HID];

    float v = 0.f;
    if (tid < 192) {
        for (int chn = 0; chn < NCHUNK; ++chn)
            v += pbk[((size_t)m * NCHUNK + chn) * 192 + tid];
    } else if (tid < 240) {
        int s = tid - 192;
        float a = 0.f;
        for (int chn = 0; chn < NCHUNK; ++chn)
            a += pS[((size_t)m * NCHUNK + chn) * 48 + s];
        S_s[s / 3][s % 3] = a;
    }
    __syncthreads();
    if (tid < 192) {
        const int kq = tid / 96, b = (tid % 96) / 32, cc = tid % 32;
        const float4* hb = (const float4*)(hpT + (size_t)m * HP_W + kq * 512 + cc * 16);
        float4 h0 = hb[0], h1 = hb[1], h2 = hb[2], h3 = hb[3];
        v += h0.x * S_s[0][b] + h0.y * S_s[1][b] + h0.z * S_s[2][b] + h0.w * S_s[3][b]
           + h1.x * S_s[4][b] + h1.y * S_s[5][b] + h1.z * S_s[6][b] + h1.w * S_s[7][b]
           + h2.x * S_s[8][b] + h2.y * S_s[9][b] + h2.z * S_s[10][b] + h2.w * S_s[11][b]
           + h3.x * S_s[12][b] + h3.y * S_s[13][b] + h3.z * S_s[14][b] + h3.w * S_s[15][b];
        bkq_s[kq][cc][b] = v;
    }
    __syncthreads();
    if (tid < HID) {
        float a = bkq_s[0][tid][0] * bkq_s[1][tid][0]
                + bkq_s[0][tid][1] * bkq_s[1][tid][1]
                + bkq_s[0][tid][2] * bkq_s[1][tid][2];
        silu_s[tid] = a / (1.0f + __expf(-a));
    }
    __syncthreads();
    if (tid < 128) {
        float acc = bsum[tid];
        const float* wr = Wsum + tid * HID;
#pragma unroll
        for (int c2 = 0; c2 < HID; ++c2) acc += wr[c2] * silu_s[c2];
        outv[(size_t)m * 128 + tid] = acc;
    }
}

// ---------------- kernel 4: K2/Q2 expansion, 64 n per block, NT coalesced stores ----------------
__global__ __launch_bounds__(256) void k_expand(const float* __restrict__ outv,
                                                float* __restrict__ out) {
    const int bid = blockIdx.x;            // 384*6
    const int m = bid / 6;
    const int n0 = (bid % 6) * 64;
    const int tid = threadIdx.x;
    __shared__ float4 om[32];
    if (tid < 32) om[tid] = ((const float4*)(outv + (size_t)m * 128))[tid];
    __syncthreads();
    const int ni = tid >> 4;
    const int r = tid & 15;
    const float4 a0 = om[2 * r], a1 = om[2 * r + 1];
    f4* o4 = (f4*)out;
#pragma unroll
    for (int sub = 0; sub < 4; ++sub) {
        const int n = n0 + sub * 16 + ni;
        const float4* on = (const float4*)(outv + (size_t)n * 128);
        float4 b0 = on[2 * r], b1 = on[2 * r + 1];
        f4 k2 = {a0.x + b0.x, a0.y + b0.y, a0.z + b0.z, a0.w + b0.w};
        f4 q2 = {a1.x + b1.x, a1.y + b1.y, a1.z + b1.z, a1.w + b1.w};
        const size_t idx = ((size_t)(m * NN + n) * RR + r);
        __builtin_nontemporal_store(k2, o4 + idx);
        __builtin_nontemporal_store(q2, o4 + (size_t)NN * NN * RR + idx);
    }
}

extern "C" void kernel_launch(void* const* d_in, const int* in_sizes, int n_in,
                              void* d_out, int out_size, void* d_ws, size_t ws_size,
                              hipStream_t stream) {
    const float* x    = (const float*)d_in[0];
    const float* h    = (const float*)d_in[1];
    const float* Wfc  = (const float*)d_in[2];
    const float* Wsum = (const float*)d_in[3];
    const float* bsum = (const float*)d_in[4];
    float* out = (float*)d_out;

    float* hpT  = (float*)d_ws;                         // 384*1024
    float* pbk  = hpT + (size_t)NN * HP_W;              // 384*8*192
    float* pS   = pbk + (size_t)NN * NCHUNK * 192;      // 384*8*48
    float* outv = pS + (size_t)NN * NCHUNK * 48;        // 384*128

    double startd = exp(-5.0);
    double rd = (2.0 / 16.0) * (1.0 - startd);
    float beta = (float)(1.0 / (rd * rd));
    float start = (float)startd;

    k_hp<<<NN, 256, 0, stream>>>(h, Wfc, hpT);
    k_mid<<<dim3(NCHUNK, NN / MT), 256, 0, stream>>>(x, hpT, pbk, pS, beta, start);
    k_combine<<<NN, 256, 0, stream>>>(hpT, Wsum, bsum, pbk, pS, outv);
    k_expand<<<NN * 6, 256, 0, stream>>>(outv, out);
}